// Round 5
// baseline (313.707 us; speedup 1.0000x reference)
//
#include <hip/hip_runtime.h>
#include <hip/hip_fp16.h>
#include <stdint.h>

// Problem constants (fixed: M=N=K=4096).
// Harness dtype reality (deduced r1-r3): x,lut,out are float32 buffers
// (reference fp16 upconverted); packed_weight is int32 (one byte per word).
#define M_DIM 4096
#define N_DIM 4096
#define K_DIM 4096
#define BM 128
#define BN 128
#define BK 32
#define KW (K_DIM / 2)

typedef _Float16 half8 __attribute__((ext_vector_type(8)));   // 4 VGPRs (MFMA A/B)
typedef float f32x4 __attribute__((ext_vector_type(4)));      // MFMA accumulator

__device__ __forceinline__ uint32_t pk2(float a, float b) {
  // packed f32->f16 (RTZ; exact here since all values are fp16-representable)
  auto h = __builtin_amdgcn_cvt_pkrtz(a, b);  // a -> low halfword
  return __builtin_bit_cast(uint32_t, h);
}

// Pre-pass: x f32 [M,K] -> fp16 bits in d_ws. One float4 per thread.
__global__ __launch_bounds__(256) void cvt_x_kernel(const float4* __restrict__ xin,
                                                    uint2* __restrict__ xout) {
  const int i = blockIdx.x * 256 + threadIdx.x;   // float4 index, grid covers exactly
  const float4 v = xin[i];
  xout[i] = make_uint2(pk2(v.x, v.y), pk2(v.z, v.w));
}

// y[m][n] = sum_k x[m][k] * W[n][k]; W dequantized from packed fp4 via LUT.
// 128x128 tile, BK=32, 4 waves (2x2), 4x4 grid of 16x16x32 f16 MFMA per wave.
// PRECONV=true: A staged from fp16 ws via global_load_lds (16B width).
// PRECONV=false: A converted inline from f32 (fallback if ws too small).
template <bool PRECONV>
__global__ __launch_bounds__(256, 2) void fp4gemm_kernel(
    const void* __restrict__ xv,       // fp16 bits [M,K] (ws) or f32 [M,K]
    const int* __restrict__ pw,        // [N, K/2] int32, one packed byte per word
    const float* __restrict__ lutf,    // 16 float LUT values
    float* __restrict__ out)           // [M, N] float32
{
  __shared__ uint16_t ldsA[BM * BK];   // [128][32] fp16 (contiguous: global_load_lds)
  __shared__ uint16_t ldsB[BN * BK];   // [128][32] fp16 (dequantized W tile, rows = n)
  __shared__ uint32_t lutp[256];       // byte -> (f16 even-k | f16 odd-k << 16)

  const int tid  = threadIdx.x;
  const int lane = tid & 63;
  const int wave = tid >> 6;
  const int wm   = wave >> 1;          // 64-row half of M tile
  const int wn   = wave & 1;           // 64-col half of N tile
  const int m0 = blockIdx.y * BM;
  const int n0 = blockIdx.x * BN;

  // byte -> fp16-pair dequant table (high nibble = even k -> low halfword)
  {
    const int hi = (tid >> 4) & 15, lo = tid & 15;
    lutp[tid] = pk2(lutf[hi], lutf[lo]);
  }

  f32x4 acc[4][4];
#pragma unroll
  for (int i = 0; i < 4; ++i)
#pragma unroll
    for (int j = 0; j < 4; ++j) acc[i][j] = (f32x4){0.f, 0.f, 0.f, 0.f};

  // B staging: thread t -> row (n) = t>>1, half-row = t&1 (8 packed words each)
  const int rowB  = tid >> 1;
  const int halfB = tid & 1;

  for (int kt = 0; kt < K_DIM / BK; ++kt) {
    __syncthreads();  // prev compute done before LDS overwrite (covers lutp on kt=0)

    // ---- Stage A: 128x32 fp16 = 8 KB ----
    if constexpr (PRECONV) {
      const uint8_t* xh = (const uint8_t*)xv;
#pragma unroll
      for (int s = 0; s < 2; ++s) {
        const int idx = tid + s * 256;        // 0..511 16B chunks
        const int row = idx >> 2;             // 64 B per A row
        const int c16 = idx & 3;
        const uint8_t* gp = xh + ((size_t)(m0 + row) * K_DIM + kt * BK) * 2 + c16 * 16;
        uint8_t* lp = (uint8_t*)ldsA + (size_t)idx * 16;  // = wave base + lane*16
        __builtin_amdgcn_global_load_lds(
            (const __attribute__((address_space(1))) uint32_t*)gp,
            (__attribute__((address_space(3))) uint32_t*)lp, 16, 0, 0);
      }
    } else {
      const float* xf = (const float*)xv;
#pragma unroll
      for (int s = 0; s < 4; ++s) {
        const int c   = tid + s * 256;        // 0..1023 float4 chunks
        const int row = c >> 3;               // 8 float4 per 32-float A row
        const int c4  = c & 7;
        const float4 v = *(const float4*)(xf + (size_t)(m0 + row) * K_DIM + kt * BK + c4 * 4);
        *(uint2*)((uint8_t*)ldsA + row * 64 + c4 * 8) =
            make_uint2(pk2(v.x, v.y), pk2(v.z, v.w));
      }
    }

    // ---- Stage B: 8 packed words (8 bytes -> 16 weights) per thread ----
    {
      const int* gp = pw + (size_t)(n0 + rowB) * KW + kt * (BK / 2) + halfB * 8;
      const int4 wA = ((const int4*)gp)[0];
      const int4 wB = ((const int4*)gp)[1];
      const uint32_t p0 = lutp[wA.x & 255], p1 = lutp[wA.y & 255];
      const uint32_t p2 = lutp[wA.z & 255], p3 = lutp[wA.w & 255];
      const uint32_t p4 = lutp[wB.x & 255], p5 = lutp[wB.y & 255];
      const uint32_t p6 = lutp[wB.z & 255], p7 = lutp[wB.w & 255];
      uint32_t* lb = (uint32_t*)((uint8_t*)ldsB + rowB * 64 + halfB * 32);
      ((uint4*)lb)[0] = make_uint4(p0, p1, p2, p3);
      ((uint4*)lb)[1] = make_uint4(p4, p5, p6, p7);
    }

    __syncthreads();

    // ---- Compute: 4 A-frags x 4 B-frags, 16 MFMAs ----
    // Identical (lane,j)->k indexing on A and B sides: any k-permutation cancels.
    half8 af[4], bfr[4];
#pragma unroll
    for (int i = 0; i < 4; ++i) {
      const uint16_t* pa = ldsA + (wm * 64 + i * 16 + (lane & 15)) * BK + (lane >> 4) * 8;
      af[i] = *(const half8*)pa;
    }
#pragma unroll
    for (int j = 0; j < 4; ++j) {
      const uint16_t* pb = ldsB + (wn * 64 + j * 16 + (lane & 15)) * BK + (lane >> 4) * 8;
      bfr[j] = *(const half8*)pb;
    }
#pragma unroll
    for (int i = 0; i < 4; ++i)
#pragma unroll
      for (int j = 0; j < 4; ++j)
        acc[i][j] = __builtin_amdgcn_mfma_f32_16x16x32_f16(af[i], bfr[j], acc[i][j], 0, 0, 0);
  }

  // ---- Epilogue: C/D layout col(n) = lane&15, row(m) = (lane>>4)*4 + reg ----
  const int mb = m0 + wm * 64 + (lane >> 4) * 4;
  const int nb = n0 + wn * 64 + (lane & 15);
#pragma unroll
  for (int i = 0; i < 4; ++i)
#pragma unroll
    for (int j = 0; j < 4; ++j)
#pragma unroll
      for (int r = 0; r < 4; ++r)
        out[(size_t)(mb + i * 16 + r) * N_DIM + (nb + j * 16)] = acc[i][j][r];
}

extern "C" void kernel_launch(void* const* d_in, const int* in_sizes, int n_in,
                              void* d_out, int out_size, void* d_ws, size_t ws_size,
                              hipStream_t stream) {
  // Size-based dispatch (element counts are dtype-independent and unique).
  const void* px = nullptr; const void* ppw = nullptr; const void* plut = nullptr;
  for (int i = 0; i < n_in; ++i) {
    const long s = in_sizes[i];
    if (s == (long)M_DIM * K_DIM) px = d_in[i];
    else if (s == (long)N_DIM * KW) ppw = d_in[i];
    else if (s == 16) plut = d_in[i];
  }
  if (!px || !ppw || !plut) { px = d_in[0]; ppw = d_in[1]; plut = d_in[2]; }

  dim3 grid(N_DIM / BN, M_DIM / BM);  // (32, 32)
  const size_t xh_bytes = (size_t)M_DIM * K_DIM * 2;  // 32 MB fp16 staging

  if (ws_size >= xh_bytes) {
    cvt_x_kernel<<<(M_DIM * K_DIM / 4) / 256, 256, 0, stream>>>(
        (const float4*)px, (uint2*)d_ws);
    fp4gemm_kernel<true><<<grid, dim3(256), 0, stream>>>(
        d_ws, (const int*)ppw, (const float*)plut, (float*)d_out);
  } else {
    fp4gemm_kernel<false><<<grid, dim3(256), 0, stream>>>(
        px, (const int*)ppw, (const float*)plut, (float*)d_out);
  }
}